// Round 9
// baseline (223.368 us; speedup 1.0000x reference)
//
#include <hip/hip_runtime.h>
#include <hip/hip_bf16.h>
#include <float.h>

#define D 64
#define K 512
#define HW 1024
#define DHW (D * HW)
#define N_PTS 65536
#define OUT_ELEMS (64 * D * HW)     /* 4,194,304 */
#define LOSS_OFF OUT_ELEMS
#define IDX_OFF (OUT_ELEMS + 1)
#define PTS_PER_BLOCK 64
#define NBLOCKS (N_PTS / PTS_PER_BLOCK)   /* 1024 */

typedef unsigned short ushort_t;
typedef unsigned long long ull_t;
typedef __attribute__((ext_vector_type(8))) short bf16x8;
typedef __attribute__((ext_vector_type(4))) float f32x4;

union U16x8 { uint4 u; bf16x8 v; ushort_t s[8]; };

__device__ __forceinline__ ushort_t f2bf(float v) {
    __hip_bfloat16 h = __float2bfloat16(v);
    return *reinterpret_cast<ushort_t*>(&h);
}
__device__ __forceinline__ float bf2f(ushort_t u) {
    unsigned int x = ((unsigned int)u) << 16;
    return *reinterpret_cast<float*>(&x);
}

// monotone float -> u32 (order-preserving for all finite floats)
__device__ __forceinline__ unsigned int f2ord(float s) {
    unsigned int u = __float_as_uint(s);
    return (u & 0x80000000u) ? ~u : (u | 0x80000000u);
}
__device__ __forceinline__ float ord2f(unsigned int o) {
    unsigned int b = (o & 0x80000000u) ? (o ^ 0x80000000u) : ~o;
    return __uint_as_float(b);
}
// 64-bit shuffle via two 32-bit shfl_xor (avoid relying on ull overload)
__device__ __forceinline__ ull_t shfl_xor_u64(ull_t v, int mask) {
    unsigned int lo = (unsigned int)v, hi = (unsigned int)(v >> 32);
    lo = __shfl_xor((int)lo, mask);
    hi = __shfl_xor((int)hi, mask);
    return ((ull_t)hi << 32) | (ull_t)lo;
}
// merge two descending-sorted pairs -> top-2 of the four
__device__ __forceinline__ void top2_merge(ull_t& k1, ull_t& k2,
                                           ull_t o1, ull_t o2) {
    ull_t n1 = k1 > o1 ? k1 : o1;
    ull_t lo = k1 > o1 ? o1 : k1;
    ull_t hi2 = k2 > o2 ? k2 : o2;
    k2 = lo > hi2 ? lo : hi2;
    k1 = n1;
}

// ---------------------------------------------------------------------------
// numpy pairwise-sum (n=64): 8 accumulators over squares, combined
// ((r0+r1)+(r2+r3))+((r4+r5)+(r6+r7)); all adds/muls un-contracted.
// ---------------------------------------------------------------------------
__device__ __forceinline__ float np_sumsq64(const float* v) {
    float r[8];
#pragma unroll
    for (int j = 0; j < 8; ++j) r[j] = __fmul_rn(v[j], v[j]);
#pragma unroll
    for (int i = 8; i < D; i += 8) {
#pragma unroll
        for (int j = 0; j < 8; ++j)
            r[j] = __fadd_rn(r[j], __fmul_rn(v[i + j], v[i + j]));
    }
    return __fadd_rn(
        __fadd_rn(__fadd_rn(r[0], r[1]), __fadd_rn(r[2], r[3])),
        __fadd_rn(__fadd_rn(r[4], r[5]), __fadd_rn(r[6], r[7])));
}

// ---------------------------------------------------------------------------
// Prep kernel (8 blocks x 64): thread = code k.
// e2[k]: ||e_k||^2 numpy order; bhi: bf16 B-fragments (layout verified r6);
// mpart[b]: block max |e - bf16(e)|.
// ---------------------------------------------------------------------------
__global__ void vq_prep_kernel(const float* __restrict__ cb,
                               float* __restrict__ e2,
                               uint4* __restrict__ bhi,
                               float* __restrict__ mpart) {
    const int k = blockIdx.x * 64 + threadIdx.x;
    float row[D];
#pragma unroll
    for (int d = 0; d < D; ++d) row[d] = cb[k * D + d];
    e2[k] = np_sumsq64(row);

    float mmax = 0.f;
#pragma unroll
    for (int kh = 0; kh < 2; ++kh) {
#pragma unroll
        for (int g = 0; g < 4; ++g) {
            U16x8 u;
#pragma unroll
            for (int i = 0; i < 8; ++i) {
                float v = row[kh * 32 + g * 8 + i];
                ushort_t h = f2bf(v);
                u.s[i] = h;
                mmax = fmaxf(mmax, fabsf(__fsub_rn(v, bf2f(h))));
            }
            bhi[kh * 2048 + (k >> 4) * 64 + g * 16 + (k & 15)] = u.u;
        }
    }
#pragma unroll
    for (int off = 32; off > 0; off >>= 1)
        mmax = fmaxf(mmax, __shfl_down(mmax, off));
    if (threadIdx.x == 0) mpart[blockIdx.x] = mmax;
}

// ---------------------------------------------------------------------------
// Main VQ: MFMA filter + deterministic top-2 + exact fallback.
// Block = 64 points, 4 waves. Wave w: points [(w>>1)*32,+32), code half w&1.
// Round-9 change: the LDS-atomic candidate collector (r6-r8) is replaced by
// an order-invariant sortable-key top-2 reduction — no atomics anywhere, so
// the kernel is bit-deterministic across replays by construction (r8's
// post-timing idx divergence came from that machinery's scheduling
// sensitivity). Gap > margin => winner immediately; else exact 512-code
// block-parallel scan with the bit-exact numpy chain (validated r2-r8).
// ---------------------------------------------------------------------------
__global__ __launch_bounds__(256, 2) void vq_main_kernel(
        const float* __restrict__ z, const float* __restrict__ cb,
        const float* __restrict__ e2, const uint4* __restrict__ bhi,
        const float* __restrict__ mpart, float* __restrict__ out,
        float* __restrict__ partial) {
    __shared__ float x_lds[D][65];          // pad 65: conflict-free
    __shared__ float q_lds[D][65];          // gathered codebook rows
    __shared__ float e2_lds[K];
    __shared__ float A_np[64];
    __shared__ float sabs[64];
    __shared__ ull_t top2_l[64][2][2];      // [point][chalf][k1,k2]
    __shared__ int   ids[64];
    __shared__ int   need[64];
    __shared__ ull_t rd_key[256];
    __shared__ float wsum[4];

    const int t     = threadIdx.x;
    const int l     = t & 63;
    const int w     = t >> 6;
    const int chalf = w & 1;
    const int p0    = (w >> 1) * 32;
    const int n0    = blockIdx.x * PTS_PER_BLOCK;
    const int b     = n0 >> 10;
    const int hw0   = n0 & 1023;

    const float M_EL = fmaxf(fmaxf(fmaxf(mpart[0], mpart[1]),
                                   fmaxf(mpart[2], mpart[3])),
                             fmaxf(fmaxf(mpart[4], mpart[5]),
                                   fmaxf(mpart[6], mpart[7])));

    // ---- stage x (coalesced), e2 ----
    const float* zb = z + b * DHW + hw0;
#pragma unroll
    for (int i = 0; i < 16; ++i) {
        const int d = w * 16 + i;
        x_lds[d][l] = zb[d * HW + l];
    }
    e2_lds[t]       = e2[t];
    e2_lds[t + 256] = e2[t + 256];
    __syncthreads();

    // wave 0: numpy-pairwise ||x||^2 and sum|x| per point (same-thread
    // consumers only until after later barriers)
    if (w == 0) {
        float r[8];
        float sa = 0.f;
#pragma unroll
        for (int j = 0; j < 8; ++j) {
            float v = x_lds[j][l];
            r[j] = __fmul_rn(v, v);
            sa += fabsf(v);
        }
#pragma unroll
        for (int d = 8; d < D; ++d) {
            float v = x_lds[d][l];
            r[d & 7] = __fadd_rn(r[d & 7], __fmul_rn(v, v));
            sa += fabsf(v);
        }
        A_np[l] = __fadd_rn(
            __fadd_rn(__fadd_rn(r[0], r[1]), __fadd_rn(r[2], r[3])),
            __fadd_rn(__fadd_rn(r[4], r[5]), __fadd_rn(r[6], r[7])));
        sabs[l] = sa;
    }

    // ---- A fragments (hi + exact lo residual), layout verified r6 ----
    bf16x8 ah[2][2], al[2][2];
#pragma unroll
    for (int Mt = 0; Mt < 2; ++Mt) {
#pragma unroll
        for (int kh = 0; kh < 2; ++kh) {
            const int pt = p0 + Mt * 16 + (l & 15);
            const int d0 = kh * 32 + ((l >> 4) << 3);
            U16x8 uh, ul;
#pragma unroll
            for (int i = 0; i < 8; ++i) {
                float v = x_lds[d0 + i][pt];
                ushort_t h = f2bf(v);
                uh.s[i] = h;
                ul.s[i] = f2bf(__fsub_rn(v, bf2f(h)));
            }
            ah[Mt][kh] = uh.v;
            al[Mt][kh] = ul.v;
        }
    }

    // ---- MFMA: C = (xh + xl) . eh ; B coalesced from global (L2-hot) ----
    f32x4 c[2][16];
#pragma unroll
    for (int Mt = 0; Mt < 2; ++Mt)
#pragma unroll
        for (int nt = 0; nt < 16; ++nt) c[Mt][nt] = (f32x4){0.f, 0.f, 0.f, 0.f};

#pragma unroll
    for (int kh = 0; kh < 2; ++kh) {
#pragma unroll
        for (int ntL = 0; ntL < 16; ++ntL) {
            U16x8 bu;
            bu.u = bhi[kh * 2048 + (chalf * 16 + ntL) * 64 + l];
            c[0][ntL] = __builtin_amdgcn_mfma_f32_16x16x32_bf16(ah[0][kh], bu.v, c[0][ntL], 0, 0, 0);
            c[1][ntL] = __builtin_amdgcn_mfma_f32_16x16x32_bf16(ah[1][kh], bu.v, c[1][ntL], 0, 0, 0);
            c[0][ntL] = __builtin_amdgcn_mfma_f32_16x16x32_bf16(al[0][kh], bu.v, c[0][ntL], 0, 0, 0);
            c[1][ntL] = __builtin_amdgcn_mfma_f32_16x16x32_bf16(al[1][kh], bu.v, c[1][ntL], 0, 0, 0);
        }
    }

    // ---- top-2 pass: per point, key = (ord(score)<<32)|(511-code) ----
    // score = C - 0.5*||e||^2; max-key => max score, ties -> lowest code.
#pragma unroll
    for (int Mt = 0; Mt < 2; ++Mt) {
#pragma unroll
        for (int r = 0; r < 4; ++r) {
            ull_t k1 = 0, k2 = 0;
#pragma unroll
            for (int ntL = 0; ntL < 16; ++ntL) {
                const int code = chalf * 256 + ntL * 16 + (l & 15);
                const float B = e2_lds[code];
                float s = __builtin_fmaf(B, -0.5f, c[Mt][ntL][r]);
                ull_t key = ((ull_t)f2ord(s) << 32) | (ull_t)(511 - code);
                if (key > k1) { k2 = k1; k1 = key; }
                else if (key > k2) { k2 = key; }
            }
#pragma unroll
            for (int mask = 1; mask < 16; mask <<= 1) {
                ull_t o1 = shfl_xor_u64(k1, mask);
                ull_t o2 = shfl_xor_u64(k2, mask);
                top2_merge(k1, k2, o1, o2);
            }
            if ((l & 15) == 0) {
                const int p = p0 + Mt * 16 + (l >> 4) * 4 + r;
                top2_l[p][chalf][0] = k1;
                top2_l[p][chalf][1] = k2;
            }
        }
    }
    __syncthreads();

    // ---- decision (t<64 = wave 0): merge halves, gap test ----
    if (t < 64) {
        ull_t k1 = top2_l[t][0][0], k2 = top2_l[t][0][1];
        top2_merge(k1, k2, top2_l[t][1][0], top2_l[t][1][1]);
        const float s1 = ord2f((unsigned int)(k1 >> 32));
        const float s2 = ord2f((unsigned int)(k2 >> 32));
        const int code1 = 511 - (int)(k1 & 0xffffffffull);
        const float tau = 4.0e-5f + 2.0f * sabs[t] * M_EL;  // rigorous margin
        if (s1 - s2 > tau) {
            ids[t] = code1;
            out[IDX_OFF + n0 + t] = (float)code1;
            need[t] = 0;
        } else {
            need[t] = 1;
        }
    }
    __syncthreads();

    // ---- exact fallback: flagged points, deterministic ascending order ----
    for (int p = 0; p < 64; ++p) {
        if (!need[p]) continue;            // uniform LDS read -> uniform branch
        float bd = FLT_MAX; int bk = 1 << 30;
#pragma unroll
        for (int half = 0; half < 2; ++half) {
            const int k = t + half * 256;
            float acc = 0.f;
            for (int d = 0; d < D; ++d)
                acc = __builtin_fmaf(x_lds[d][p], cb[k * D + d], acc);
            float dist = __fsub_rn(__fadd_rn(A_np[p], e2_lds[k]), 2.0f * acc);
            if (dist < bd || (dist == bd && k < bk)) { bd = dist; bk = k; }
        }
        rd_key[t] = ((ull_t)f2ord(bd) << 32) | (ull_t)bk;   // min-key
        __syncthreads();
        for (int off = 128; off > 0; off >>= 1) {
            if (t < off) {
                ull_t o = rd_key[t + off];
                if (o < rd_key[t]) rd_key[t] = o;
            }
            __syncthreads();
        }
        if (t == 0) {
            const int kwin = (int)(rd_key[0] & 0xffffffffull);
            ids[p] = kwin;
            out[IDX_OFF + n0 + p] = (float)kwin;
        }
        __syncthreads();
    }

    // ---- E1: cooperative coalesced gather of chosen rows -> q_lds ----
#pragma unroll
    for (int pb = 0; pb < 64; pb += 4) {
        const int p = pb + w;              // wave w gathers point pb+w
        q_lds[l][p] = cb[ids[p] * D + l];  // one 256B contiguous row read
    }
    __syncthreads();

    // ---- E2: out = fl(x + fl(q - x)) coalesced, loss partials ----
    float* ob = out + b * DHW + hw0;
    float lsum = 0.f;
#pragma unroll
    for (int i = 0; i < 16; ++i) {
        const int d  = w * 16 + i;
        const float xv   = x_lds[d][l];
        const float q    = q_lds[d][l];
        const float diff = __fsub_rn(q, xv);
        lsum = __builtin_fmaf(diff, diff, lsum);
        ob[d * HW + l] = __fadd_rn(xv, diff);
    }
#pragma unroll
    for (int off = 32; off > 0; off >>= 1) lsum += __shfl_down(lsum, off);
    if (l == 0) wsum[w] = lsum;
    __syncthreads();
    if (t == 0)
        partial[blockIdx.x] = __fadd_rn(__fadd_rn(wsum[0], wsum[1]),
                                        __fadd_rn(wsum[2], wsum[3]));
}

// ---------------------------------------------------------------------------
// Loss kernel: reduce 1024 block partials -> loss = 1.25 * MSE
// ---------------------------------------------------------------------------
__global__ void vq_loss_kernel(const float* __restrict__ partial,
                               float* __restrict__ out) {
    __shared__ float sh[256];
    float s = 0.f;
#pragma unroll
    for (int i = 0; i < NBLOCKS / 256; ++i)
        s += partial[threadIdx.x + i * 256];
    sh[threadIdx.x] = s;
    __syncthreads();
    for (int off = 128; off > 0; off >>= 1) {
        if (threadIdx.x < off) sh[threadIdx.x] += sh[threadIdx.x + off];
        __syncthreads();
    }
    if (threadIdx.x == 0)
        out[LOSS_OFF] = 1.25f * sh[0] / (float)OUT_ELEMS;
}

extern "C" void kernel_launch(void* const* d_in, const int* in_sizes, int n_in,
                              void* d_out, int out_size, void* d_ws,
                              size_t ws_size, hipStream_t stream) {
    const float* z  = (const float*)d_in[0];   // [64, 64, 32, 32] f32
    const float* cb = (const float*)d_in[1];   // [512, 64] f32
    float* out = (float*)d_out;
    float* wsf = (float*)d_ws;
    float* e2      = wsf;                      // 512 f32
    float* partial = wsf + 512;                // 1024 f32
    float* mpart   = wsf + 1536;               // 8 f32
    uint4* bhi     = (uint4*)(wsf + 2048);     // 4096 uint4 = 64KB

    vq_prep_kernel<<<8, 64, 0, stream>>>(cb, e2, bhi, mpart);
    vq_main_kernel<<<NBLOCKS, 256, 0, stream>>>(z, cb, e2, bhi, mpart, out, partial);
    vq_loss_kernel<<<1, 256, 0, stream>>>(partial, out);
}